// Round 1
// baseline (315.084 us; speedup 1.0000x reference)
//
#include <hip/hip_runtime.h>
#include <hip/hip_bf16.h>

// ---------------------------------------------------------------------------
// AttentionLayer: out = quirky_softmax(mask * (Q K^T)) @ V
//   denom[j] = sum_k exp(mask[j,k]*S[j,k])  (row sums)
//   softmax[i,j] = E[i,j] / denom[j]        (column-indexed denom!)
//   => out = E @ (V scaled per-row by 1/denom)
// R3->R4: E + scaled-V stored in fp8 e4m3; out-GEMM in fp8 MFMA (BK=128).
// R5: GEMM K-loops converted from 2x __syncthreads (vmcnt(0) drain) to a
//     3-stage ring pipeline: stage tile t+2 while computing tile t, counted
//     s_waitcnt vmcnt(N) + raw s_barrier (never drain to 0 in steady state).
// ---------------------------------------------------------------------------

#define N_TOK 4096
#define D_DIM 1024
#define VS_SCALE 131072.0f        // 2^17: lifts V/denom (~7e-6) into fp8 range

typedef __bf16 bf16x8 __attribute__((ext_vector_type(8)));
typedef __bf16 bf16x4 __attribute__((ext_vector_type(4)));
typedef float  f32x4  __attribute__((ext_vector_type(4)));

typedef const __attribute__((address_space(1))) char g_char;
typedef __attribute__((address_space(3))) char lds_char;

__device__ inline unsigned char f32_to_fp8(float f) {
    return (unsigned char)(__builtin_amdgcn_cvt_pk_fp8_f32(f, f, 0, false) & 0xff);
}

// ---------------------------------------------------------------------------
// fp32 -> bf16 convert (blocks 0..4095) + bias concat (blocks 4096..4107)
// ---------------------------------------------------------------------------
__global__ void cvt_and_bias(const float* __restrict__ x, __bf16* __restrict__ xb,
                             const float* __restrict__ bq, const float* __restrict__ bk,
                             const float* __restrict__ bv, float* __restrict__ bcat) {
    int b = blockIdx.x;
    if (b < 4096) {
        int i = (b * 256 + threadIdx.x) * 4;
        float4 v = *(const float4*)(x + i);
        bf16x4 o;
        o.x = (__bf16)v.x; o.y = (__bf16)v.y;
        o.z = (__bf16)v.z; o.w = (__bf16)v.w;
        *(bf16x4*)(xb + i) = o;
    } else {
        int i = (b - 4096) * 256 + threadIdx.x;
        if (i < 1024) bcat[i] = bq[i];
        else if (i < 2048) bcat[i] = bk[i - 1024];
        else if (i < 3072) bcat[i] = bv[i - 2048];
    }
}

// ---------------------------------------------------------------------------
// Transpose three 1024x1024 fp32 W -> bf16 [out][in], concatenated
// ---------------------------------------------------------------------------
__global__ void transpose_w3(const float* __restrict__ Wq, const float* __restrict__ Wk,
                             const float* __restrict__ Wv, __bf16* __restrict__ outT) {
    const float* in = (blockIdx.z == 0) ? Wq : (blockIdx.z == 1) ? Wk : Wv;
    __bf16* oT = outT + (size_t)blockIdx.z * 1024 * 1024;
    __shared__ float t[64][65];
    const int c0 = blockIdx.x * 64, r0 = blockIdx.y * 64;
    const int tid = threadIdx.x;
#pragma unroll
    for (int k = 0; k < 16; k++) {
        int lin = tid + k * 256;
        int r = lin >> 6, c = lin & 63;
        t[r][c] = in[(size_t)(r0 + r) * 1024 + c0 + c];
    }
    __syncthreads();
#pragma unroll
    for (int k = 0; k < 16; k++) {
        int lin = tid + k * 256;
        int c = lin >> 6, r = lin & 63;
        oT[(size_t)(c0 + c) * 1024 + r0 + r] = (__bf16)t[r][c];
    }
}

// ---------------------------------------------------------------------------
// VsT[d][j] = fp8( VS_SCALE * V[j][d] / denom[j] ), V row stride ldv
// ---------------------------------------------------------------------------
__global__ void scale_transpose(const __bf16* __restrict__ V, int ldv,
                                const float* __restrict__ denom,
                                unsigned char* __restrict__ VT8) {
    __shared__ float t[64][65];
    __shared__ float rd[64];
    const int d0 = blockIdx.x * 64, j0 = blockIdx.y * 64;
    const int tid = threadIdx.x;
    if (tid < 64) rd[tid] = VS_SCALE / denom[j0 + tid];
    __syncthreads();
#pragma unroll
    for (int k = 0; k < 16; k++) {
        int lin = tid + k * 256;
        int j = lin >> 6, d = lin & 63;
        t[j][d] = (float)V[(size_t)(j0 + j) * ldv + d0 + d] * rd[j];
    }
    __syncthreads();
#pragma unroll
    for (int k = 0; k < 16; k++) {
        int lin = tid + k * 256;
        int d = lin >> 6, j = lin & 63;
        VT8[(size_t)(d0 + d) * N_TOK + j0 + j] = f32_to_fp8(t[j][d]);
    }
}

// ---------------------------------------------------------------------------
// NT GEMM (bf16): C = A * B^T, fp32 acc, BK=64, 128x128 tile, XOR-swizzled LDS.
// 3-stage ring pipeline (96 KB LDS, 1 block/CU): stage tile t+2 while
// computing tile t; counted vmcnt(8) (= loads of newest tile) forces tile t+1
// landed; raw s_barrier (NO vmcnt(0) drain in steady state).
// EPI 0: Cb = bf16(acc + bias[col])
// EPI 1: C8 = fp8(exp(mask[idx]*acc)); denom[row] += rowsum (atomic, pre-round)
// ---------------------------------------------------------------------------
template <int EPI>
__global__ __launch_bounds__(256, 2)
void gemm_nt(const __bf16* __restrict__ A, const __bf16* __restrict__ B,
             int lda, int ldb, int ldc, int K,
             const float* __restrict__ bias,
             const float* __restrict__ mask,
             __bf16* __restrict__ Cb, unsigned char* __restrict__ C8,
             float* __restrict__ denom) {
    __shared__ __bf16 lA[3 * 128 * 64];   // 3 x 16 KB
    __shared__ __bf16 lB[3 * 128 * 64];   // 3 x 16 KB

    const int tid  = threadIdx.x;
    const int wave = tid >> 6;
    const int lane = tid & 63;
    const int quad = lane >> 4;
    const int l16  = lane & 15;
    const int m0 = blockIdx.y * 128;
    const int n0 = blockIdx.x * 128;
    const int wr = (wave >> 1) * 64;
    const int wc = (wave & 1) * 64;

    // staging: LDS 16B-chunk p=c*256+tid holds global chunk ((p&7)^((p>>3)&7))
    // of row (p>>3); swizzle is pass-invariant (pass step 32 rows = 0 mod 8).
    const size_t lda_b = (size_t)lda * 2;
    const size_t ldb_b = (size_t)ldb * 2;
    const int tr = tid >> 3;
    const int ts = ((tid & 7) ^ (tr & 7)) * 16;
    const char* gA = (const char*)A + (size_t)(m0 + tr) * lda_b + ts;
    const char* gB = (const char*)B + (size_t)(n0 + tr) * ldb_b + ts;
    const size_t pstepA = (size_t)32 * lda_b;
    const size_t pstepB = (size_t)32 * ldb_b;

    lds_char* lAs = (lds_char*)(void*)lA + wave * 1024;
    lds_char* lBs = (lds_char*)(void*)lB + wave * 1024;

    // read addrs: frag chunk = ks*4+quad, swizzled pos = chunk^(l16&7)
    const int l7 = l16 & 7;
    const int rdA0 = ((wr + l16) * 128 + ((quad ^ l7) * 16)) >> 1;
    const int rdA1 = ((wr + l16) * 128 + (((4 + quad) ^ l7) * 16)) >> 1;
    const int rdB0 = ((wc + l16) * 128 + ((quad ^ l7) * 16)) >> 1;
    const int rdB1 = ((wc + l16) * 128 + (((4 + quad) ^ l7) * 16)) >> 1;

    f32x4 acc[4][4];
#pragma unroll
    for (int i = 0; i < 4; i++)
#pragma unroll
        for (int j = 0; j < 4; j++) acc[i][j] = (f32x4){0.f, 0.f, 0.f, 0.f};

    const int NT = K >> 6;

    // issue order per tile: A0..A3, B0..B3 (8 loads) -- vmcnt math relies on it
#define STAGE_NT(tt, bb) do {                                                         \
    const char* ga_ = gA + (size_t)(tt) * 128;                                        \
    const char* gb_ = gB + (size_t)(tt) * 128;                                        \
    lds_char* la_ = lAs + (bb) * 16384;                                               \
    lds_char* lb_ = lBs + (bb) * 16384;                                               \
    __builtin_amdgcn_global_load_lds((g_char*)(ga_),              la_,         16, 0, 0); \
    __builtin_amdgcn_global_load_lds((g_char*)(ga_ + pstepA),     la_ + 4096,  16, 0, 0); \
    __builtin_amdgcn_global_load_lds((g_char*)(ga_ + 2 * pstepA), la_ + 8192,  16, 0, 0); \
    __builtin_amdgcn_global_load_lds((g_char*)(ga_ + 3 * pstepA), la_ + 12288, 16, 0, 0); \
    __builtin_amdgcn_global_load_lds((g_char*)(gb_),              lb_,         16, 0, 0); \
    __builtin_amdgcn_global_load_lds((g_char*)(gb_ + pstepB),     lb_ + 4096,  16, 0, 0); \
    __builtin_amdgcn_global_load_lds((g_char*)(gb_ + 2 * pstepB), lb_ + 8192,  16, 0, 0); \
    __builtin_amdgcn_global_load_lds((g_char*)(gb_ + 3 * pstepB), lb_ + 12288, 16, 0, 0); \
} while (0)

    // prologue: stage tiles 0,1; wait oldest 8 (= tile 0) landed
    STAGE_NT(0, 0);
    STAGE_NT(1, 1);
    asm volatile("s_waitcnt vmcnt(8)" ::: "memory");
    __builtin_amdgcn_s_barrier();
    __builtin_amdgcn_sched_barrier(0);

    for (int t = 0; t < NT; ++t) {
        const int b = t % 3;
        const bool pf = (t + 2 < NT);
        if (pf) STAGE_NT(t + 2, (t + 2) % 3);

        const __bf16* la = lA + b * 8192;
        const __bf16* lb = lB + b * 8192;

        bf16x8 a0[4], a1[4], bf0[4], bf1[4];
#pragma unroll
        for (int i = 0; i < 4; i++) {
            a0[i] = *(const bf16x8*)&la[rdA0 + i * 1024];
            a1[i] = *(const bf16x8*)&la[rdA1 + i * 1024];
        }
#pragma unroll
        for (int j = 0; j < 4; j++) {
            bf0[j] = *(const bf16x8*)&lb[rdB0 + j * 1024];
            bf1[j] = *(const bf16x8*)&lb[rdB1 + j * 1024];
        }
        __builtin_amdgcn_s_setprio(1);
#pragma unroll
        for (int i = 0; i < 4; i++)
#pragma unroll
            for (int j = 0; j < 4; j++)
                acc[i][j] = __builtin_amdgcn_mfma_f32_16x16x32_bf16(
                    a0[i], bf0[j], acc[i][j], 0, 0, 0);
#pragma unroll
        for (int i = 0; i < 4; i++)
#pragma unroll
            for (int j = 0; j < 4; j++)
                acc[i][j] = __builtin_amdgcn_mfma_f32_16x16x32_bf16(
                    a1[i], bf1[j], acc[i][j], 0, 0, 0);
        __builtin_amdgcn_s_setprio(0);
        __builtin_amdgcn_sched_barrier(0);
        // steady: allow newest tile's 8 loads to float -> tile t+1 forced landed.
        // tails (no prefetch issued): drain so tile t+1 is guaranteed.
        if (pf) asm volatile("s_waitcnt vmcnt(8) lgkmcnt(0)" ::: "memory");
        else    asm volatile("s_waitcnt vmcnt(0) lgkmcnt(0)" ::: "memory");
        __builtin_amdgcn_s_barrier();
        __builtin_amdgcn_sched_barrier(0);
    }
#undef STAGE_NT

    // epilogue: C/D layout col=lane&15, row=quad*4+reg
#pragma unroll
    for (int i = 0; i < 4; i++) {
        const int rbase = m0 + wr + i * 16 + quad * 4;
        f32x4 rs = (f32x4){0.f, 0.f, 0.f, 0.f};
#pragma unroll
        for (int j = 0; j < 4; j++) {
            const int col = n0 + wc + j * 16 + l16;
            f32x4 v = acc[i][j];
            if (EPI == 0) {
                const float bb = bias[col];
#pragma unroll
                for (int r = 0; r < 4; r++)
                    Cb[(size_t)(rbase + r) * ldc + col] = (__bf16)(v[r] + bb);
            } else {
#pragma unroll
                for (int r = 0; r < 4; r++) {
                    size_t idx = (size_t)(rbase + r) * ldc + col;
                    float e = __expf(mask[idx] * v[r]);
                    C8[idx] = f32_to_fp8(e);
                    rs[r] += e;   // pre-round sum: bias contribution ~5e-6, negligible
                }
            }
        }
        if (EPI == 1) {
#pragma unroll
            for (int m = 1; m < 16; m <<= 1) {
#pragma unroll
                for (int r = 0; r < 4; r++) rs[r] += __shfl_xor(rs[r], m, 64);
            }
            if (l16 == 0) {
#pragma unroll
                for (int r = 0; r < 4; r++) atomicAdd(&denom[rbase + r], rs[r]);
            }
        }
    }
}

// ---------------------------------------------------------------------------
// out GEMM (fp8): C[4096][1024] = E[4096][4096] * VsT[1024][4096]^T, BK=128.
// 128x64 tile, 4 waves each 64x32 (4x2 frags). LDS byte layout identical to
// bf16 BK=64 swizzle. 3-stage ring pipeline (72 KB LDS, 2 blocks/CU), counted
// vmcnt(6) (= 6 loads of newest tile), raw s_barrier.
// ---------------------------------------------------------------------------
__global__ __launch_bounds__(256, 2)
void gemm_out_fp8(const unsigned char* __restrict__ A,
                  const unsigned char* __restrict__ B,
                  float* __restrict__ C) {
    __shared__ unsigned char lA[3 * 128 * 128];  // 3 x 16 KB
    __shared__ unsigned char lB[3 * 64 * 128];   // 3 x 8 KB

    const int tid  = threadIdx.x;
    const int wave = tid >> 6;
    const int lane = tid & 63;
    const int quad = lane >> 4;
    const int l16  = lane & 15;
    const int m0 = blockIdx.y * 128;
    const int n0 = blockIdx.x * 64;
    const int wr = (wave >> 1) * 64;
    const int wc = (wave & 1) * 32;

    const int tr = tid >> 3;
    const int ts = ((tid & 7) ^ (tr & 7)) * 16;
    const char* gA = (const char*)A + (size_t)(m0 + tr) * N_TOK + ts;
    const char* gB = (const char*)B + (size_t)(n0 + tr) * N_TOK + ts;
    const size_t pstep = (size_t)32 * N_TOK;

    lds_char* lAs = (lds_char*)(void*)lA + wave * 1024;
    lds_char* lBs = (lds_char*)(void*)lB + wave * 1024;

    // read addr: row*128 + ((kstep*2 + (quad>>1)) ^ (l16&7))*16 + (quad&1)*8
    const int l7 = l16 & 7;
    const int qhi = quad >> 1, qlo = (quad & 1) * 8;
    int rdA[4], rdB[4];
#pragma unroll
    for (int k = 0; k < 4; k++) {
        rdA[k] = ((k * 2 + qhi) ^ l7) * 16 + qlo;   // add row*128 per-frag
        rdB[k] = rdA[k];
    }

    f32x4 acc[4][2];
#pragma unroll
    for (int i = 0; i < 4; i++)
#pragma unroll
        for (int j = 0; j < 2; j++) acc[i][j] = (f32x4){0.f, 0.f, 0.f, 0.f};

    const int NT = N_TOK / 128;  // 32

    // issue order per tile: A0..A3, B0..B1 (6 loads)
#define STAGE_O(tt, bb) do {                                                          \
    const char* ga_ = gA + (size_t)(tt) * 128;                                        \
    const char* gb_ = gB + (size_t)(tt) * 128;                                        \
    lds_char* la_ = lAs + (bb) * 16384;                                               \
    lds_char* lb_ = lBs + (bb) * 8192;                                                \
    __builtin_amdgcn_global_load_lds((g_char*)(ga_),             la_,         16, 0, 0); \
    __builtin_amdgcn_global_load_lds((g_char*)(ga_ + pstep),     la_ + 4096,  16, 0, 0); \
    __builtin_amdgcn_global_load_lds((g_char*)(ga_ + 2 * pstep), la_ + 8192,  16, 0, 0); \
    __builtin_amdgcn_global_load_lds((g_char*)(ga_ + 3 * pstep), la_ + 12288, 16, 0, 0); \
    __builtin_amdgcn_global_load_lds((g_char*)(gb_),             lb_,         16, 0, 0); \
    __builtin_amdgcn_global_load_lds((g_char*)(gb_ + pstep),     lb_ + 4096,  16, 0, 0); \
} while (0)

    STAGE_O(0, 0);
    STAGE_O(1, 1);
    asm volatile("s_waitcnt vmcnt(6)" ::: "memory");
    __builtin_amdgcn_s_barrier();
    __builtin_amdgcn_sched_barrier(0);

    for (int t = 0; t < NT; ++t) {
        const int b = t % 3;
        const bool pf = (t + 2 < NT);
        if (pf) STAGE_O(t + 2, (t + 2) % 3);

        const unsigned char* la = lA + b * 16384;
        const unsigned char* lb = lB + b * 8192;

        long av[4][4], bv[4][2];
#pragma unroll
        for (int k = 0; k < 4; k++) {
#pragma unroll
            for (int i = 0; i < 4; i++)
                av[k][i] = *(const long*)&la[(wr + i * 16 + l16) * 128 + rdA[k]];
#pragma unroll
            for (int j = 0; j < 2; j++)
                bv[k][j] = *(const long*)&lb[(wc + j * 16 + l16) * 128 + rdB[k]];
        }
        __builtin_amdgcn_s_setprio(1);
#pragma unroll
        for (int k = 0; k < 4; k++)
#pragma unroll
            for (int i = 0; i < 4; i++)
#pragma unroll
                for (int j = 0; j < 2; j++)
                    acc[i][j] = __builtin_amdgcn_mfma_f32_16x16x32_fp8_fp8(
                        av[k][i], bv[k][j], acc[i][j], 0, 0, 0);
        __builtin_amdgcn_s_setprio(0);
        __builtin_amdgcn_sched_barrier(0);
        if (pf) asm volatile("s_waitcnt vmcnt(6) lgkmcnt(0)" ::: "memory");
        else    asm volatile("s_waitcnt vmcnt(0) lgkmcnt(0)" ::: "memory");
        __builtin_amdgcn_s_barrier();
        __builtin_amdgcn_sched_barrier(0);
    }
#undef STAGE_O

#pragma unroll
    for (int i = 0; i < 4; i++) {
#pragma unroll
        for (int j = 0; j < 2; j++) {
            const int col   = n0 + wc + j * 16 + l16;
            const int rbase = m0 + wr + i * 16 + quad * 4;
            f32x4 v = acc[i][j];
#pragma unroll
            for (int r = 0; r < 4; r++)
                C[(size_t)(rbase + r) * D_DIM + col] = v[r] * (1.0f / VS_SCALE);
        }
    }
}

// ---------------------------------------------------------------------------
extern "C" void kernel_launch(void* const* d_in, const int* in_sizes, int n_in,
                              void* d_out, int out_size, void* d_ws, size_t ws_size,
                              hipStream_t stream) {
    const float* x    = (const float*)d_in[0];
    const float* mask = (const float*)d_in[1];
    const float* Wq   = (const float*)d_in[2];
    const float* bq   = (const float*)d_in[3];
    const float* Wk   = (const float*)d_in[4];
    const float* bk   = (const float*)d_in[5];
    const float* Wv   = (const float*)d_in[6];
    const float* bv   = (const float*)d_in[7];
    float* out = (float*)d_out;
    char* ws = (char*)d_ws;

    const size_t MB = 1024 * 1024;
    unsigned char* E8   = (unsigned char*)(ws + 0 * MB);   // 16 MB [4096][4096] fp8
    __bf16* QKVb  = (__bf16*)(ws + 16 * MB);               // 24 MB [4096][3072]
    __bf16* xb    = (__bf16*)(ws + 40 * MB);               // 8 MB [4096][1024]
    unsigned char* VsT8 = (unsigned char*)xb;              // 4 MB (reuses dead xb)
    __bf16* WcatT = (__bf16*)(ws + 48 * MB);               // 6 MB [3072][1024]
    float*  bcat  = (float*)(ws + 54 * MB);                // 12 KB
    float*  denom = (float*)(ws + 54 * MB + 64 * 1024);    // 16 KB

    hipMemsetAsync(denom, 0, N_TOK * sizeof(float), stream);

    // ---- prep ----
    cvt_and_bias<<<4096 + 12, 256, 0, stream>>>(x, xb, bq, bk, bv, bcat);
    transpose_w3<<<dim3(16, 16, 3), 256, 0, stream>>>(Wq, Wk, Wv, WcatT);

    // ---- fused QKV projection ----
    gemm_nt<0><<<dim3(24, 32), 256, 0, stream>>>(
        xb, WcatT, D_DIM, D_DIM, 3 * D_DIM, D_DIM,
        bcat, nullptr, QKVb, nullptr, nullptr);

    // ---- E = exp(mask * (Q K^T)) -> fp8; denom[row] += rowsum ----
    const __bf16* Qb = QKVb;
    const __bf16* Kb = QKVb + D_DIM;
    gemm_nt<1><<<dim3(32, 32), 256, 0, stream>>>(
        Qb, Kb, 3 * D_DIM, 3 * D_DIM, N_TOK, D_DIM,
        nullptr, mask, nullptr, E8, denom);

    // ---- VsT8[d][j] = fp8(VS_SCALE * V[j][d] / denom[j]) ----
    scale_transpose<<<dim3(16, 64), 256, 0, stream>>>(QKVb + 2048, 3 * D_DIM, denom, VsT8);

    // ---- out = (E8 @ VsT8^T) / VS_SCALE ----
    gemm_out_fp8<<<dim3(16, 32), 256, 0, stream>>>(E8, VsT8, out);
}

// Round 2
// 252.159 us; speedup vs baseline: 1.2495x; 1.2495x over previous
//
#include <hip/hip_runtime.h>
#include <hip/hip_bf16.h>

// ---------------------------------------------------------------------------
// AttentionLayer: out = quirky_softmax(mask * (Q K^T)) @ V
//   denom[j] = sum_k exp(mask[j,k]*S[j,k])  (row sums)
//   softmax[i,j] = E[i,j] / denom[j]        (column-indexed denom!)
//   => out = E @ (V scaled per-row by 1/denom)
// R4: E + scaled-V in fp8 e4m3; out-GEMM in fp8 MFMA (verified, kept as-is).
// R5: 3-buffer ring on 128^2 tile -> REGRESSED (1 block/CU, coarse ring =
//     m196 anti-pattern). Reverted.
// R6: gemm_nt ported to the m201-style 256x256 / BK=64 / 8-wave 4-phase
//     schedule: per phase {ds_read quadrant || stage -> barrier -> lgkm(0)
//     -> 16 MFMA -> barrier}, vmcnt(0) only at K-tile boundary (issued
//     2.5+ phases earlier). Same verified swizzle (pre-swizzled global src,
//     linear global_load_lds dest, XOR'd read). out_fp8 = R0-verified code.
// ---------------------------------------------------------------------------

#define N_TOK 4096
#define D_DIM 1024
#define VS_SCALE 131072.0f        // 2^17: lifts V/denom (~7e-6) into fp8 range

typedef __bf16 bf16x8 __attribute__((ext_vector_type(8)));
typedef __bf16 bf16x4 __attribute__((ext_vector_type(4)));
typedef float  f32x4  __attribute__((ext_vector_type(4)));

typedef const __attribute__((address_space(1))) char g_char;
typedef __attribute__((address_space(3))) char lds_char;

__device__ inline unsigned char f32_to_fp8(float f) {
    return (unsigned char)(__builtin_amdgcn_cvt_pk_fp8_f32(f, f, 0, false) & 0xff);
}

// ---------------------------------------------------------------------------
// fp32 -> bf16 convert (blocks 0..4095) + bias concat (blocks 4096..4107)
// ---------------------------------------------------------------------------
__global__ void cvt_and_bias(const float* __restrict__ x, __bf16* __restrict__ xb,
                             const float* __restrict__ bq, const float* __restrict__ bk,
                             const float* __restrict__ bv, float* __restrict__ bcat) {
    int b = blockIdx.x;
    if (b < 4096) {
        int i = (b * 256 + threadIdx.x) * 4;
        float4 v = *(const float4*)(x + i);
        bf16x4 o;
        o.x = (__bf16)v.x; o.y = (__bf16)v.y;
        o.z = (__bf16)v.z; o.w = (__bf16)v.w;
        *(bf16x4*)(xb + i) = o;
    } else {
        int i = (b - 4096) * 256 + threadIdx.x;
        if (i < 1024) bcat[i] = bq[i];
        else if (i < 2048) bcat[i] = bk[i - 1024];
        else if (i < 3072) bcat[i] = bv[i - 2048];
    }
}

// ---------------------------------------------------------------------------
// Transpose three 1024x1024 fp32 W -> bf16 [out][in], concatenated
// ---------------------------------------------------------------------------
__global__ void transpose_w3(const float* __restrict__ Wq, const float* __restrict__ Wk,
                             const float* __restrict__ Wv, __bf16* __restrict__ outT) {
    const float* in = (blockIdx.z == 0) ? Wq : (blockIdx.z == 1) ? Wk : Wv;
    __bf16* oT = outT + (size_t)blockIdx.z * 1024 * 1024;
    __shared__ float t[64][65];
    const int c0 = blockIdx.x * 64, r0 = blockIdx.y * 64;
    const int tid = threadIdx.x;
#pragma unroll
    for (int k = 0; k < 16; k++) {
        int lin = tid + k * 256;
        int r = lin >> 6, c = lin & 63;
        t[r][c] = in[(size_t)(r0 + r) * 1024 + c0 + c];
    }
    __syncthreads();
#pragma unroll
    for (int k = 0; k < 16; k++) {
        int lin = tid + k * 256;
        int c = lin >> 6, r = lin & 63;
        oT[(size_t)(c0 + c) * 1024 + r0 + r] = (__bf16)t[r][c];
    }
}

// ---------------------------------------------------------------------------
// VsT[d][j] = fp8( VS_SCALE * V[j][d] / denom[j] ), V row stride ldv
// ---------------------------------------------------------------------------
__global__ void scale_transpose(const __bf16* __restrict__ V, int ldv,
                                const float* __restrict__ denom,
                                unsigned char* __restrict__ VT8) {
    __shared__ float t[64][65];
    __shared__ float rd[64];
    const int d0 = blockIdx.x * 64, j0 = blockIdx.y * 64;
    const int tid = threadIdx.x;
    if (tid < 64) rd[tid] = VS_SCALE / denom[j0 + tid];
    __syncthreads();
#pragma unroll
    for (int k = 0; k < 16; k++) {
        int lin = tid + k * 256;
        int j = lin >> 6, d = lin & 63;
        t[j][d] = (float)V[(size_t)(j0 + j) * ldv + d0 + d] * rd[j];
    }
    __syncthreads();
#pragma unroll
    for (int k = 0; k < 16; k++) {
        int lin = tid + k * 256;
        int d = lin >> 6, j = lin & 63;
        VT8[(size_t)(d0 + d) * N_TOK + j0 + j] = f32_to_fp8(t[j][d]);
    }
}

// ---------------------------------------------------------------------------
// NT GEMM (bf16): C = A * B^T, fp32 acc. 256x256 tile, BK=64, 512 thr/8 waves
// (2Mx4N), per-wave 128x64 out. LDS: 2 K-tile buffers x (A 32K + B 32K) =
// 128 KB, 1 block/CU. 4 phases per K-tile:
//   phase p: {ds_read A row-frags {2p,2p+1} (+ all B in p0) ||
//             stage next K-tile (phases 0,1) -> s_barrier -> lgkmcnt(0) ->
//             setprio(1) 16 MFMA setprio(0) -> s_barrier}
// vmcnt(0) ONLY at phase-3 boundary (loads issued >=2.5 phases earlier).
// Swizzle: global chunk q of row r lives at LDS slot q^(r&7) (pre-swizzled
// global source + linear global_load_lds dest); reads XOR with l16&7.
// EPI 0: Cb = bf16(acc + bias[col])
// EPI 1: C8 = fp8(exp(mask[idx]*acc)); denom[row] += rowsum (atomic)
// ---------------------------------------------------------------------------
template <int EPI>
__global__ __launch_bounds__(512, 2)
void gemm_nt_256(const __bf16* __restrict__ A, const __bf16* __restrict__ B,
                 int lda, int ldb, int ldc, int K,
                 const float* __restrict__ bias,
                 const float* __restrict__ mask,
                 __bf16* __restrict__ Cb, unsigned char* __restrict__ C8,
                 float* __restrict__ denom) {
    __shared__ __bf16 ldsb[2 * 32768];   // 2 x 64 KB = 128 KB

    const int tid  = threadIdx.x;
    const int wave = tid >> 6;
    const int lane = tid & 63;
    const int quad = lane >> 4;
    const int l16  = lane & 15;
    const int l7   = l16 & 7;
    const int m0 = blockIdx.y * 256;
    const int n0 = blockIdx.x * 256;
    const int wr = (wave >> 2) * 128;   // 2 row groups
    const int wc = (wave & 3) * 64;     // 4 col groups

    // staging: per K-tile, A rounds 0..3 cover rows tr+{0,64,128,192};
    // global source pre-swizzled by chunk ts, LDS dest linear.
    const size_t lda_b = (size_t)lda * 2;
    const size_t ldb_b = (size_t)ldb * 2;
    const int tr = tid >> 3;                       // 0..63
    const int ts = ((tid & 7) ^ (tr & 7)) * 16;
    const char* gA = (const char*)A + (size_t)(m0 + tr) * lda_b + ts;
    const char* gB = (const char*)B + (size_t)(n0 + tr) * ldb_b + ts;
    const size_t rstepA = (size_t)64 * lda_b;
    const size_t rstepB = (size_t)64 * ldb_b;

    lds_char* lw = (lds_char*)(void*)ldsb + wave * 1024;   // wave's 8 rows/round

    // read offsets (bytes). Row r, chunk c (of 8 x 16B) at slot c^(r&7).
    const int s0 = ((0 + quad) ^ l7) * 16;   // kstep 0: chunks 0..3
    const int s1 = ((4 + quad) ^ l7) * 16;   // kstep 1: chunks 4..7
    const int aRow = (wr + l16) * 128;             // + i*2048 per row-frag
    const int bRow = (wc + l16) * 128 + 32768;     // B half at +32 KB

    f32x4 acc[8][4];
#pragma unroll
    for (int i = 0; i < 8; i++)
#pragma unroll
        for (int j = 0; j < 4; j++) acc[i][j] = (f32x4){0.f, 0.f, 0.f, 0.f};

    const int NT = K >> 6;

    // group gg in {0,1}: A rounds {2gg,2gg+1} + B rounds {2gg,2gg+1} (4 loads)
#define STAGE4(tt, bb, gg) do {                                                       \
    const char* ga_ = gA + (size_t)(tt) * 128 + (size_t)(2 * (gg)) * rstepA;          \
    const char* gb_ = gB + (size_t)(tt) * 128 + (size_t)(2 * (gg)) * rstepB;          \
    lds_char* la_ = lw + (bb) * 65536 + (2 * (gg)) * 8192;                            \
    lds_char* lb_ = lw + (bb) * 65536 + 32768 + (2 * (gg)) * 8192;                    \
    __builtin_amdgcn_global_load_lds((g_char*)(ga_),          la_,        16, 0, 0);  \
    __builtin_amdgcn_global_load_lds((g_char*)(ga_ + rstepA), la_ + 8192, 16, 0, 0);  \
    __builtin_amdgcn_global_load_lds((g_char*)(gb_),          lb_,        16, 0, 0);  \
    __builtin_amdgcn_global_load_lds((g_char*)(gb_ + rstepB), lb_ + 8192, 16, 0, 0);  \
} while (0)

    // prologue: stage K-tile 0 fully, drain, barrier
    STAGE4(0, 0, 0);
    STAGE4(0, 0, 1);
    asm volatile("s_waitcnt vmcnt(0)" ::: "memory");
    __builtin_amdgcn_s_barrier();

    for (int t = 0; t < NT; ++t) {
        const int cb = t & 1;
        const char* buf = (const char*)ldsb + cb * 65536;
        const bool pf = (t + 1 < NT);
        bf16x8 bfr[4][2];

#pragma unroll
        for (int p = 0; p < 4; p++) {
            // ---- ds-read register subtile ----
            if (p == 0) {
#pragma unroll
                for (int j = 0; j < 4; j++) {
                    bfr[j][0] = *(const bf16x8*)(buf + bRow + j * 2048 + s0);
                    bfr[j][1] = *(const bf16x8*)(buf + bRow + j * 2048 + s1);
                }
            }
            bf16x8 aF[2][2];
#pragma unroll
            for (int ii = 0; ii < 2; ii++) {
                aF[ii][0] = *(const bf16x8*)(buf + aRow + (2 * p + ii) * 2048 + s0);
                aF[ii][1] = *(const bf16x8*)(buf + aRow + (2 * p + ii) * 2048 + s1);
            }
            // ---- stage next K-tile (front-loaded: phases 0,1) ----
            if (p < 2 && pf) STAGE4(t + 1, cb ^ 1, p);

            __builtin_amdgcn_s_barrier();
            asm volatile("s_waitcnt lgkmcnt(0)" ::: "memory");
            __builtin_amdgcn_sched_barrier(0);
            __builtin_amdgcn_s_setprio(1);
#pragma unroll
            for (int ii = 0; ii < 2; ii++)
#pragma unroll
                for (int j = 0; j < 4; j++) {
                    acc[2 * p + ii][j] = __builtin_amdgcn_mfma_f32_16x16x32_bf16(
                        aF[ii][0], bfr[j][0], acc[2 * p + ii][j], 0, 0, 0);
                    acc[2 * p + ii][j] = __builtin_amdgcn_mfma_f32_16x16x32_bf16(
                        aF[ii][1], bfr[j][1], acc[2 * p + ii][j], 0, 0, 0);
                }
            __builtin_amdgcn_s_setprio(0);
            __builtin_amdgcn_sched_barrier(0);
            if (p == 3) asm volatile("s_waitcnt vmcnt(0)" ::: "memory");
            __builtin_amdgcn_s_barrier();
        }
    }
#undef STAGE4

    // epilogue: C/D layout col=lane&15, row=quad*4+reg
#pragma unroll
    for (int i = 0; i < 8; i++) {
        const int rbase = m0 + wr + i * 16 + quad * 4;
        f32x4 rs = (f32x4){0.f, 0.f, 0.f, 0.f};
#pragma unroll
        for (int j = 0; j < 4; j++) {
            const int col = n0 + wc + j * 16 + l16;
            f32x4 v = acc[i][j];
            if (EPI == 0) {
                const float bb = bias[col];
#pragma unroll
                for (int r = 0; r < 4; r++)
                    Cb[(size_t)(rbase + r) * ldc + col] = (__bf16)(v[r] + bb);
            } else {
#pragma unroll
                for (int r = 0; r < 4; r++) {
                    size_t idx = (size_t)(rbase + r) * ldc + col;
                    float e = __expf(mask[idx] * v[r]);
                    C8[idx] = f32_to_fp8(e);
                    rs[r] += e;   // pre-round sum: bias contribution ~5e-6, negligible
                }
            }
        }
        if (EPI == 1) {
#pragma unroll
            for (int m = 1; m < 16; m <<= 1) {
#pragma unroll
                for (int r = 0; r < 4; r++) rs[r] += __shfl_xor(rs[r], m, 64);
            }
            if (l16 == 0) {
#pragma unroll
                for (int r = 0; r < 4; r++) atomicAdd(&denom[rbase + r], rs[r]);
            }
        }
    }
}

// ---------------------------------------------------------------------------
// out GEMM (fp8): C[4096][1024] = E[4096][4096] * VsT[1024][4096]^T, BK=128.
// 128x64 tile, 4 waves each 64x32 (4x2 frags). (R0-verified version.)
// ---------------------------------------------------------------------------
__global__ __launch_bounds__(256, 2)
void gemm_out_fp8(const unsigned char* __restrict__ A,
                  const unsigned char* __restrict__ B,
                  float* __restrict__ C) {
    __shared__ unsigned char lA[128 * 128];
    __shared__ unsigned char lB[64 * 128];

    const int tid  = threadIdx.x;
    const int wave = tid >> 6;
    const int lane = tid & 63;
    const int quad = lane >> 4;
    const int l16  = lane & 15;
    const int m0 = blockIdx.y * 128;
    const int n0 = blockIdx.x * 64;
    const int wr = (wave >> 1) * 64;
    const int wc = (wave & 1) * 32;

    const int tr = tid >> 3;
    const int ts = ((tid & 7) ^ (tr & 7)) * 16;
    const char* gA = (const char*)A + (size_t)(m0 + tr) * N_TOK + ts;
    const char* gB = (const char*)B + (size_t)(n0 + tr) * N_TOK + ts;
    const size_t pstep = (size_t)32 * N_TOK;

    lds_char* lAp = (lds_char*)(void*)lA + wave * 1024;
    lds_char* lBp = (lds_char*)(void*)lB + wave * 1024;

    // read addr: row*128 + ((kstep*2 + (quad>>1)) ^ (l16&7))*16 + (quad&1)*8
    const int l7 = l16 & 7;
    const int qhi = quad >> 1, qlo = (quad & 1) * 8;
    int rdA[4], rdB[4];
#pragma unroll
    for (int k = 0; k < 4; k++) {
        rdA[k] = ((k * 2 + qhi) ^ l7) * 16 + qlo;   // add row*128 per-frag
        rdB[k] = rdA[k];
    }

    f32x4 acc[4][2];
#pragma unroll
    for (int i = 0; i < 4; i++)
#pragma unroll
        for (int j = 0; j < 2; j++) acc[i][j] = (f32x4){0.f, 0.f, 0.f, 0.f};

    for (int kt = 0; kt < N_TOK; kt += 128) {
#pragma unroll
        for (int c = 0; c < 4; c++)
            __builtin_amdgcn_global_load_lds((g_char*)(gA + c * pstep),
                                             lAp + c * 4096, 16, 0, 0);
#pragma unroll
        for (int c = 0; c < 2; c++)
            __builtin_amdgcn_global_load_lds((g_char*)(gB + c * pstep),
                                             lBp + c * 4096, 16, 0, 0);
        gA += 128;
        gB += 128;
        __syncthreads();

#pragma unroll
        for (int k = 0; k < 4; k++) {
            long a[4], b[2];
#pragma unroll
            for (int i = 0; i < 4; i++)
                a[i] = *(const long*)&lA[(wr + i * 16 + l16) * 128 + rdA[k]];
#pragma unroll
            for (int j = 0; j < 2; j++)
                b[j] = *(const long*)&lB[(wc + j * 16 + l16) * 128 + rdB[k]];
#pragma unroll
            for (int i = 0; i < 4; i++)
#pragma unroll
                for (int j = 0; j < 2; j++)
                    acc[i][j] = __builtin_amdgcn_mfma_f32_16x16x32_fp8_fp8(
                        a[i], b[j], acc[i][j], 0, 0, 0);
        }
        __syncthreads();
    }

#pragma unroll
    for (int i = 0; i < 4; i++) {
#pragma unroll
        for (int j = 0; j < 2; j++) {
            const int col   = n0 + wc + j * 16 + l16;
            const int rbase = m0 + wr + i * 16 + quad * 4;
            f32x4 v = acc[i][j];
#pragma unroll
            for (int r = 0; r < 4; r++)
                C[(size_t)(rbase + r) * D_DIM + col] = v[r] * (1.0f / VS_SCALE);
        }
    }
}

// ---------------------------------------------------------------------------
extern "C" void kernel_launch(void* const* d_in, const int* in_sizes, int n_in,
                              void* d_out, int out_size, void* d_ws, size_t ws_size,
                              hipStream_t stream) {
    const float* x    = (const float*)d_in[0];
    const float* mask = (const float*)d_in[1];
    const float* Wq   = (const float*)d_in[2];
    const float* bq   = (const float*)d_in[3];
    const float* Wk   = (const float*)d_in[4];
    const float* bk   = (const float*)d_in[5];
    const float* Wv   = (const float*)d_in[6];
    const float* bv   = (const float*)d_in[7];
    float* out = (float*)d_out;
    char* ws = (char*)d_ws;

    const size_t MB = 1024 * 1024;
    unsigned char* E8   = (unsigned char*)(ws + 0 * MB);   // 16 MB [4096][4096] fp8
    __bf16* QKVb  = (__bf16*)(ws + 16 * MB);               // 24 MB [4096][3072]
    __bf16* xb    = (__bf16*)(ws + 40 * MB);               // 8 MB [4096][1024]
    unsigned char* VsT8 = (unsigned char*)xb;              // 4 MB (reuses dead xb)
    __bf16* WcatT = (__bf16*)(ws + 48 * MB);               // 6 MB [3072][1024]
    float*  bcat  = (float*)(ws + 54 * MB);                // 12 KB
    float*  denom = (float*)(ws + 54 * MB + 64 * 1024);    // 16 KB

    hipMemsetAsync(denom, 0, N_TOK * sizeof(float), stream);

    // ---- prep ----
    cvt_and_bias<<<4096 + 12, 256, 0, stream>>>(x, xb, bq, bk, bv, bcat);
    transpose_w3<<<dim3(16, 16, 3), 256, 0, stream>>>(Wq, Wk, Wv, WcatT);

    // ---- fused QKV projection: [4096][3072] = xb @ WcatT^T ----
    gemm_nt_256<0><<<dim3(12, 16), 512, 0, stream>>>(
        xb, WcatT, D_DIM, D_DIM, 3 * D_DIM, D_DIM,
        bcat, nullptr, QKVb, nullptr, nullptr);

    // ---- E = exp(mask * (Q K^T)) -> fp8; denom[row] += rowsum ----
    const __bf16* Qb = QKVb;
    const __bf16* Kb = QKVb + D_DIM;
    gemm_nt_256<1><<<dim3(16, 16), 512, 0, stream>>>(
        Qb, Kb, 3 * D_DIM, 3 * D_DIM, N_TOK, D_DIM,
        nullptr, mask, nullptr, E8, denom);

    // ---- VsT8[d][j] = fp8(VS_SCALE * V[j][d] / denom[j]) ----
    scale_transpose<<<dim3(16, 64), 256, 0, stream>>>(QKVb + 2048, 3 * D_DIM, denom, VsT8);

    // ---- out = (E8 @ VsT8^T) / VS_SCALE ----
    gemm_out_fp8<<<dim3(16, 32), 256, 0, stream>>>(E8, VsT8, out);
}

// Round 3
// 249.645 us; speedup vs baseline: 1.2621x; 1.0101x over previous
//
#include <hip/hip_runtime.h>
#include <hip/hip_bf16.h>

// ---------------------------------------------------------------------------
// AttentionLayer: out = quirky_softmax(mask * (Q K^T)) @ V
//   denom[j] = sum_k exp(mask[j,k]*S[j,k])  (row sums)
//   softmax[i,j] = E[i,j] / denom[j]        (column-indexed denom!)
//   => out = E @ (V scaled per-row by 1/denom)
// R4: E + scaled-V in fp8 e4m3; out-GEMM in fp8 MFMA (verified, kept as-is).
// R5: 3-buf ring on 128^2 -> regressed (occupancy collapse). Reverted.
// R6: 256^2 4-phase, but still vmcnt(0)-drained at K-tile boundary -> ~545 TF
//     (the m218 "8-phase-with-drain == null" case).
// R7: counted-vmcnt ring: 4 half-K-tile slots (BK=32, 4x32KB LDS). Per phase:
//     wait vmcnt(8) -> barrier -> stage half h+3 -> 12 ds_read_b128 ->
//     32 MFMA. 2 halves always in flight across barriers; drain only in the
//     2-phase tail. New f(r)=(r>>1)&3 chunk swizzle (2-way = free).
// ---------------------------------------------------------------------------

#define N_TOK 4096
#define D_DIM 1024
#define VS_SCALE 131072.0f        // 2^17: lifts V/denom (~7e-6) into fp8 range

typedef __bf16 bf16x8 __attribute__((ext_vector_type(8)));
typedef __bf16 bf16x4 __attribute__((ext_vector_type(4)));
typedef float  f32x4  __attribute__((ext_vector_type(4)));

typedef const __attribute__((address_space(1))) char g_char;
typedef __attribute__((address_space(3))) char lds_char;

__device__ inline unsigned char f32_to_fp8(float f) {
    return (unsigned char)(__builtin_amdgcn_cvt_pk_fp8_f32(f, f, 0, false) & 0xff);
}

// ---------------------------------------------------------------------------
// fp32 -> bf16 convert (blocks 0..4095) + bias concat (blocks 4096..4107)
// ---------------------------------------------------------------------------
__global__ void cvt_and_bias(const float* __restrict__ x, __bf16* __restrict__ xb,
                             const float* __restrict__ bq, const float* __restrict__ bk,
                             const float* __restrict__ bv, float* __restrict__ bcat) {
    int b = blockIdx.x;
    if (b < 4096) {
        int i = (b * 256 + threadIdx.x) * 4;
        float4 v = *(const float4*)(x + i);
        bf16x4 o;
        o.x = (__bf16)v.x; o.y = (__bf16)v.y;
        o.z = (__bf16)v.z; o.w = (__bf16)v.w;
        *(bf16x4*)(xb + i) = o;
    } else {
        int i = (b - 4096) * 256 + threadIdx.x;
        if (i < 1024) bcat[i] = bq[i];
        else if (i < 2048) bcat[i] = bk[i - 1024];
        else if (i < 3072) bcat[i] = bv[i - 2048];
    }
}

// ---------------------------------------------------------------------------
// Transpose three 1024x1024 fp32 W -> bf16 [out][in], concatenated
// ---------------------------------------------------------------------------
__global__ void transpose_w3(const float* __restrict__ Wq, const float* __restrict__ Wk,
                             const float* __restrict__ Wv, __bf16* __restrict__ outT) {
    const float* in = (blockIdx.z == 0) ? Wq : (blockIdx.z == 1) ? Wk : Wv;
    __bf16* oT = outT + (size_t)blockIdx.z * 1024 * 1024;
    __shared__ float t[64][65];
    const int c0 = blockIdx.x * 64, r0 = blockIdx.y * 64;
    const int tid = threadIdx.x;
#pragma unroll
    for (int k = 0; k < 16; k++) {
        int lin = tid + k * 256;
        int r = lin >> 6, c = lin & 63;
        t[r][c] = in[(size_t)(r0 + r) * 1024 + c0 + c];
    }
    __syncthreads();
#pragma unroll
    for (int k = 0; k < 16; k++) {
        int lin = tid + k * 256;
        int c = lin >> 6, r = lin & 63;
        oT[(size_t)(c0 + c) * 1024 + r0 + r] = (__bf16)t[r][c];
    }
}

// ---------------------------------------------------------------------------
// VsT[d][j] = fp8( VS_SCALE * V[j][d] / denom[j] ), V row stride ldv
// ---------------------------------------------------------------------------
__global__ void scale_transpose(const __bf16* __restrict__ V, int ldv,
                                const float* __restrict__ denom,
                                unsigned char* __restrict__ VT8) {
    __shared__ float t[64][65];
    __shared__ float rd[64];
    const int d0 = blockIdx.x * 64, j0 = blockIdx.y * 64;
    const int tid = threadIdx.x;
    if (tid < 64) rd[tid] = VS_SCALE / denom[j0 + tid];
    __syncthreads();
#pragma unroll
    for (int k = 0; k < 16; k++) {
        int lin = tid + k * 256;
        int j = lin >> 6, d = lin & 63;
        t[j][d] = (float)V[(size_t)(j0 + j) * ldv + d0 + d] * rd[j];
    }
    __syncthreads();
#pragma unroll
    for (int k = 0; k < 16; k++) {
        int lin = tid + k * 256;
        int d = lin >> 6, j = lin & 63;
        VT8[(size_t)(d0 + d) * N_TOK + j0 + j] = f32_to_fp8(t[j][d]);
    }
}

// ---------------------------------------------------------------------------
// NT GEMM (bf16): C = A * B^T, fp32 acc. 256x256 tile, 512 thr / 8 waves
// (2Mx4N), per-wave 128x64 out. Counted-vmcnt ring pipeline:
//   staging unit = half-K-tile (BK=32): A 256x32 (16KB) + B 256x32 (16KB)
//   = one 32KB slot; ring of 4 slots = 128 KB LDS.
//   per phase h: [wait vmcnt(8) -> s_barrier -> stage half h+3 (4 gload_lds)
//                 -> 12 ds_read_b128 -> 32 MFMA]
//   steady state keeps halves h+1,h+2 (8 loads) in flight across the barrier;
//   tail: vmcnt(4) then vmcnt(0).
// Swizzle (rule #21): rows are 64B = 4x16B chunks; global chunk c of row r
// stored at LDS chunk c ^ f(r), f(r)=(r>>1)&3 (pre-swizzled global source,
// linear global_load_lds dest). Read XORs the same f -> 2-way banks (free).
// EPI 0: Cb = bf16(acc + bias[col])
// EPI 1: C8 = fp8(exp(mask[idx]*acc)); denom[row] += rowsum (atomic)
// ---------------------------------------------------------------------------
template <int EPI>
__global__ __launch_bounds__(512, 2)
void gemm_nt_256(const __bf16* __restrict__ A, const __bf16* __restrict__ B,
                 int lda, int ldb, int ldc, int K,
                 const float* __restrict__ bias,
                 const float* __restrict__ mask,
                 __bf16* __restrict__ Cb, unsigned char* __restrict__ C8,
                 float* __restrict__ denom) {
    __shared__ __bf16 ldsb[4 * 16384];   // 4 slots x 32 KB = 128 KB

    const int tid  = threadIdx.x;
    const int wave = tid >> 6;
    const int lane = tid & 63;
    const int quad = lane >> 4;
    const int l16  = lane & 15;

    // bijective XCD swizzle on linear block id (nwg % 8 == 0 at our grids)
    const int nbx = gridDim.x;
    const int nwg = gridDim.x * gridDim.y;
    const int bid = blockIdx.y * nbx + blockIdx.x;
    const int cpx = nwg >> 3;
    const int swz = (bid & 7) * cpx + (bid >> 3);
    const int m0 = (swz / nbx) * 256;
    const int n0 = (swz % nbx) * 256;

    const int wr = (wave >> 2) * 128;   // 2 row groups
    const int wc = (wave & 3) * 64;     // 4 col groups

    // ---- staging addresses (per-thread) ----
    // round = 512 thr x 16B = 8 KB = 128 rows x 64 B. thread t: row t>>2,
    // LDS chunk t&3 (linear dest), global chunk (t&3) ^ f(row), f=(row>>1)&3
    // = (t>>3)&3. A-half = 2 rounds (rows 0-127, 128-255); B-half same.
    const size_t lda_b = (size_t)lda * 2;
    const size_t ldb_b = (size_t)ldb * 2;
    const int trow = tid >> 2;
    const int tcs  = ((tid & 3) ^ ((tid >> 3) & 3)) * 16;
    const char* gA = (const char*)A + (size_t)(m0 + trow) * lda_b + tcs;
    const char* gB = (const char*)B + (size_t)(n0 + trow) * ldb_b + tcs;
    const size_t rstepA = 128 * lda_b;
    const size_t rstepB = 128 * ldb_b;

    lds_char* lw = (lds_char*)(void*)ldsb + tid * 16;

    // ---- read addresses ----
    // frag row = wr + i*16 + l16; bits 1-2 of row come from l16 only.
    const int cswz = (quad ^ ((l16 >> 1) & 3)) * 16;
    const int aOff = (wr + l16) * 64 + cswz;            // + i*1024 per frag
    const int bOff = (wc + l16) * 64 + cswz + 16384;    // + j*1024 per frag

    f32x4 acc[8][4];
#pragma unroll
    for (int i = 0; i < 8; i++)
#pragma unroll
        for (int j = 0; j < 4; j++) acc[i][j] = (f32x4){0.f, 0.f, 0.f, 0.f};

    const int H = K >> 5;   // number of BK=32 halves

    // stage half hh into slot hh&3 (4 gload_lds, issue order fixed)
#define STAGEH(hh) do {                                                              \
    const char* ga_ = gA + (size_t)(hh) * 64;                                        \
    const char* gb_ = gB + (size_t)(hh) * 64;                                        \
    lds_char* ls_ = lw + ((hh) & 3) * 32768;                                         \
    __builtin_amdgcn_global_load_lds((g_char*)(ga_),          ls_,          16, 0, 0); \
    __builtin_amdgcn_global_load_lds((g_char*)(ga_ + rstepA), ls_ + 8192,   16, 0, 0); \
    __builtin_amdgcn_global_load_lds((g_char*)(gb_),          ls_ + 16384,  16, 0, 0); \
    __builtin_amdgcn_global_load_lds((g_char*)(gb_ + rstepB), ls_ + 24576,  16, 0, 0); \
} while (0)

    // prologue: stage halves 0,1,2 (12 loads in flight)
    STAGEH(0);
    STAGEH(1);
    STAGEH(2);

    for (int h = 0; h < H; ++h) {
        // staged-through = min(h+2, H-1); allow (staged-through - h) halves
        if (h + 2 < H)      asm volatile("s_waitcnt vmcnt(8)" ::: "memory");
        else if (h + 1 < H) asm volatile("s_waitcnt vmcnt(4)" ::: "memory");
        else                asm volatile("s_waitcnt vmcnt(0)" ::: "memory");
        __builtin_amdgcn_s_barrier();
        __builtin_amdgcn_sched_barrier(0);
        if (h + 3 < H) STAGEH(h + 3);

        const char* sb = (const char*)ldsb + (h & 3) * 32768;
        bf16x8 af[8], bfr[4];
#pragma unroll
        for (int i = 0; i < 8; i++) af[i] = *(const bf16x8*)(sb + aOff + i * 1024);
#pragma unroll
        for (int j = 0; j < 4; j++) bfr[j] = *(const bf16x8*)(sb + bOff + j * 1024);

        __builtin_amdgcn_s_setprio(1);
#pragma unroll
        for (int i = 0; i < 8; i++)
#pragma unroll
            for (int j = 0; j < 4; j++)
                acc[i][j] = __builtin_amdgcn_mfma_f32_16x16x32_bf16(
                    af[i], bfr[j], acc[i][j], 0, 0, 0);
        __builtin_amdgcn_s_setprio(0);
        __builtin_amdgcn_sched_barrier(0);
    }
#undef STAGEH

    // epilogue: C/D layout col=lane&15, row=quad*4+reg
#pragma unroll
    for (int i = 0; i < 8; i++) {
        const int rbase = m0 + wr + i * 16 + quad * 4;
        f32x4 rs = (f32x4){0.f, 0.f, 0.f, 0.f};
#pragma unroll
        for (int j = 0; j < 4; j++) {
            const int col = n0 + wc + j * 16 + l16;
            f32x4 v = acc[i][j];
            if (EPI == 0) {
                const float bb = bias[col];
#pragma unroll
                for (int r = 0; r < 4; r++)
                    Cb[(size_t)(rbase + r) * ldc + col] = (__bf16)(v[r] + bb);
            } else {
#pragma unroll
                for (int r = 0; r < 4; r++) {
                    size_t idx = (size_t)(rbase + r) * ldc + col;
                    float e = __expf(mask[idx] * v[r]);
                    C8[idx] = f32_to_fp8(e);
                    rs[r] += e;   // pre-round sum: bias contribution ~5e-6, negligible
                }
            }
        }
        if (EPI == 1) {
#pragma unroll
            for (int m = 1; m < 16; m <<= 1) {
#pragma unroll
                for (int r = 0; r < 4; r++) rs[r] += __shfl_xor(rs[r], m, 64);
            }
            if (l16 == 0) {
#pragma unroll
                for (int r = 0; r < 4; r++) atomicAdd(&denom[rbase + r], rs[r]);
            }
        }
    }
}

// ---------------------------------------------------------------------------
// out GEMM (fp8): C[4096][1024] = E[4096][4096] * VsT[1024][4096]^T, BK=128.
// 128x64 tile, 4 waves each 64x32 (4x2 frags). (R0-verified version.)
// ---------------------------------------------------------------------------
__global__ __launch_bounds__(256, 2)
void gemm_out_fp8(const unsigned char* __restrict__ A,
                  const unsigned char* __restrict__ B,
                  float* __restrict__ C) {
    __shared__ unsigned char lA[128 * 128];
    __shared__ unsigned char lB[64 * 128];

    const int tid  = threadIdx.x;
    const int wave = tid >> 6;
    const int lane = tid & 63;
    const int quad = lane >> 4;
    const int l16  = lane & 15;
    const int m0 = blockIdx.y * 128;
    const int n0 = blockIdx.x * 64;
    const int wr = (wave >> 1) * 64;
    const int wc = (wave & 1) * 32;

    const int tr = tid >> 3;
    const int ts = ((tid & 7) ^ (tr & 7)) * 16;
    const char* gA = (const char*)A + (size_t)(m0 + tr) * N_TOK + ts;
    const char* gB = (const char*)B + (size_t)(n0 + tr) * N_TOK + ts;
    const size_t pstep = (size_t)32 * N_TOK;

    lds_char* lAp = (lds_char*)(void*)lA + wave * 1024;
    lds_char* lBp = (lds_char*)(void*)lB + wave * 1024;

    // read addr: row*128 + ((kstep*2 + (quad>>1)) ^ (l16&7))*16 + (quad&1)*8
    const int l7 = l16 & 7;
    const int qhi = quad >> 1, qlo = (quad & 1) * 8;
    int rdA[4], rdB[4];
#pragma unroll
    for (int k = 0; k < 4; k++) {
        rdA[k] = ((k * 2 + qhi) ^ l7) * 16 + qlo;   // add row*128 per-frag
        rdB[k] = rdA[k];
    }

    f32x4 acc[4][2];
#pragma unroll
    for (int i = 0; i < 4; i++)
#pragma unroll
        for (int j = 0; j < 2; j++) acc[i][j] = (f32x4){0.f, 0.f, 0.f, 0.f};

    for (int kt = 0; kt < N_TOK; kt += 128) {
#pragma unroll
        for (int c = 0; c < 4; c++)
            __builtin_amdgcn_global_load_lds((g_char*)(gA + c * pstep),
                                             lAp + c * 4096, 16, 0, 0);
#pragma unroll
        for (int c = 0; c < 2; c++)
            __builtin_amdgcn_global_load_lds((g_char*)(gB + c * pstep),
                                             lBp + c * 4096, 16, 0, 0);
        gA += 128;
        gB += 128;
        __syncthreads();

#pragma unroll
        for (int k = 0; k < 4; k++) {
            long a[4], b[2];
#pragma unroll
            for (int i = 0; i < 4; i++)
                a[i] = *(const long*)&lA[(wr + i * 16 + l16) * 128 + rdA[k]];
#pragma unroll
            for (int j = 0; j < 2; j++)
                b[j] = *(const long*)&lB[(wc + j * 16 + l16) * 128 + rdB[k]];
#pragma unroll
            for (int i = 0; i < 4; i++)
#pragma unroll
                for (int j = 0; j < 2; j++)
                    acc[i][j] = __builtin_amdgcn_mfma_f32_16x16x32_fp8_fp8(
                        a[i], b[j], acc[i][j], 0, 0, 0);
        }
        __syncthreads();
    }

#pragma unroll
    for (int i = 0; i < 4; i++) {
#pragma unroll
        for (int j = 0; j < 2; j++) {
            const int col   = n0 + wc + j * 16 + l16;
            const int rbase = m0 + wr + i * 16 + quad * 4;
            f32x4 v = acc[i][j];
#pragma unroll
            for (int r = 0; r < 4; r++)
                C[(size_t)(rbase + r) * D_DIM + col] = v[r] * (1.0f / VS_SCALE);
        }
    }
}

// ---------------------------------------------------------------------------
extern "C" void kernel_launch(void* const* d_in, const int* in_sizes, int n_in,
                              void* d_out, int out_size, void* d_ws, size_t ws_size,
                              hipStream_t stream) {
    const float* x    = (const float*)d_in[0];
    const float* mask = (const float*)d_in[1];
    const float* Wq   = (const float*)d_in[2];
    const float* bq   = (const float*)d_in[3];
    const float* Wk   = (const float*)d_in[4];
    const float* bk   = (const float*)d_in[5];
    const float* Wv   = (const float*)d_in[6];
    const float* bv   = (const float*)d_in[7];
    float* out = (float*)d_out;
    char* ws = (char*)d_ws;

    const size_t MB = 1024 * 1024;
    unsigned char* E8   = (unsigned char*)(ws + 0 * MB);   // 16 MB [4096][4096] fp8
    __bf16* QKVb  = (__bf16*)(ws + 16 * MB);               // 24 MB [4096][3072]
    __bf16* xb    = (__bf16*)(ws + 40 * MB);               // 8 MB [4096][1024]
    unsigned char* VsT8 = (unsigned char*)xb;              // 4 MB (reuses dead xb)
    __bf16* WcatT = (__bf16*)(ws + 48 * MB);               // 6 MB [3072][1024]
    float*  bcat  = (float*)(ws + 54 * MB);                // 12 KB
    float*  denom = (float*)(ws + 54 * MB + 64 * 1024);    // 16 KB

    hipMemsetAsync(denom, 0, N_TOK * sizeof(float), stream);

    // ---- prep ----
    cvt_and_bias<<<4096 + 12, 256, 0, stream>>>(x, xb, bq, bk, bv, bcat);
    transpose_w3<<<dim3(16, 16, 3), 256, 0, stream>>>(Wq, Wk, Wv, WcatT);

    // ---- fused QKV projection: [4096][3072] = xb @ WcatT^T ----
    gemm_nt_256<0><<<dim3(12, 16), 512, 0, stream>>>(
        xb, WcatT, D_DIM, D_DIM, 3 * D_DIM, D_DIM,
        bcat, nullptr, QKVb, nullptr, nullptr);

    // ---- E = exp(mask * (Q K^T)) -> fp8; denom[row] += rowsum ----
    const __bf16* Qb = QKVb;
    const __bf16* Kb = QKVb + D_DIM;
    gemm_nt_256<1><<<dim3(16, 16), 512, 0, stream>>>(
        Qb, Kb, 3 * D_DIM, 3 * D_DIM, N_TOK, D_DIM,
        nullptr, mask, nullptr, E8, denom);

    // ---- VsT8[d][j] = fp8(VS_SCALE * V[j][d] / denom[j]) ----
    scale_transpose<<<dim3(16, 64), 256, 0, stream>>>(QKVb + 2048, 3 * D_DIM, denom, VsT8);

    // ---- out = (E8 @ VsT8^T) / VS_SCALE ----
    gemm_out_fp8<<<dim3(16, 32), 256, 0, stream>>>(E8, VsT8, out);
}